// Round 18
// baseline (119.412 us; speedup 1.0000x reference)
//
#include <hip/hip_runtime.h>
#include <hip/hip_bf16.h>

// Problem constants: B=16, N=16384, D=256, grid 128x128, K=3 depthwise, GELU.
// coords = per-batch permutation of all cells -> collision-free, min=(0,0).
//
// R18: MLP probe. One output row per wave (3-row window), DEPTH-2 pinned
// column prefetch (5 column buffers in flight), 4096 blocks -> 32 waves/CU
// (occupancy cap). Doubles in-flight loads per wave AND resident waves vs
// R14. If dur drops -> per-wave MLP was the limiter; if flat -> CU-level
// outstanding-miss cap => scattered-1KB roofline reached.
#define BB 16
#define NN 16384
#define GW 128
#define TSX 16           // tile width
#define TSY 4            // tile height (1 row per wave)
#define HSX 18
#define HSY 6

typedef float f32x4 __attribute__((ext_vector_type(4)));

// ---------------------------------------------------------------------------
// Kernel 1: inverse permutation + zero-row init
// ---------------------------------------------------------------------------
__global__ __launch_bounds__(256) void build_inv_kernel(
    const int* __restrict__ coords, int* __restrict__ inv,
    float* __restrict__ zrow) {
  int i = blockIdx.x * blockDim.x + threadIdx.x;   // 0 .. B*N-1
  int b = i >> 14;
  int gx = coords[2 * (size_t)i];
  int gy = coords[2 * (size_t)i + 1];
  inv[(b << 14) + (gy << 7) + gx] = i & (NN - 1);
  if (blockIdx.x == 0) zrow[threadIdx.x] = 0.0f;   // 256 floats = 1 row
}

__device__ __forceinline__ float gelu_fast(float a) {
  // gelu_tanh(a) = a * sigmoid(1.5957691216*(a + 0.044715*a^3))
  const float s = a * a;
  const float t = fmaf(0.044715f * a, s, a);
  const float e = __builtin_amdgcn_exp2f(t * -2.3022083f);
  return a * __builtin_amdgcn_rcpf(1.0f + e);
}

// wave-relative halo index k = r*18 + j, r in 0..2, j in 0..17 (54 < 64:
// single lane-packed VGPR, extracted with imm v_readlane)
#define HIDX(k) __builtin_amdgcn_readlane(vIdx, (k))

// load halo column j (3 stacked rows r0..r0+2) for this lane's 4 channels
#define LCOL(j, col)                                                      \
  _Pragma("unroll") for (int r3 = 0; r3 < 3; ++r3) {                      \
    const int n_ = HIDX(r3 * HSX + (j));                                  \
    const float* p_ = (n_ >= 0) ? xb + ((size_t)n_ << 8) : zrow;          \
    col[r3] = *(const f32x4*)(p_ + c4);                                   \
  }

// ---------------------------------------------------------------------------
// Kernel 2: 16x4 tile; wave w -> tile row w; lane -> 4 channels (f32x4).
// ---------------------------------------------------------------------------
__global__ __launch_bounds__(256) void mixer_kernel(
    const float* __restrict__ x, const float* __restrict__ cw,
    const float* __restrict__ cb, const int* __restrict__ inv,
    const float* __restrict__ zrow, float* __restrict__ out) {
  const int id = blockIdx.x;               // 4096 blocks
  const int rem = id >> 3;                 // 0..511
  const int b = ((id & 7) << 1) + (rem >> 8);   // XCD-swizzled batch
  const int tile = rem & 255;              // 256 tiles/batch (32 x 8)
  const int gy0 = (tile >> 3) * TSY;
  const int gx0 = (tile & 7) * TSX;

  const int tid = threadIdx.x;
  const int lane = tid & 63;
  const int wv = tid >> 6;
  const int c4 = lane << 2;                // first channel of this lane
  const int r0 = wv;                       // wave's halo row base

  // ---- lane-packed halo indices for THIS wave (k = r*18 + j, 54 total) ----
  const int* __restrict__ invb = inv + (b << 14);
  int vIdx;
  {
    const int r_ = lane / HSX, j_ = lane - r_ * HSX;   // lane 0..53 valid
    const int gy_ = gy0 - 1 + r0 + r_, gx_ = gx0 - 1 + j_;
    vIdx = (lane < 3 * HSX && (unsigned)gy_ < (unsigned)GW &&
            (unsigned)gx_ < (unsigned)GW)
               ? invb[(gy_ << 7) + gx_] : -1;
  }

  // per-lane weights/bias for channels c4..c4+3
  f32x4 wq[9], bq;
#pragma unroll
  for (int cc = 0; cc < 4; ++cc) {
    bq[cc] = cb[c4 + cc];
#pragma unroll
    for (int j = 0; j < 9; ++j) wq[j][cc] = cw[(c4 + cc) * 9 + j];
  }

  const float* __restrict__ xb = x + ((size_t)b << 22);
  float* __restrict__ ob = out + ((size_t)b << 22);

  // 3-column window + 2 in-flight prefetch columns (all static after unroll)
  f32x4 cA[3], cB[3], cC[3], cD[3], cE[3];
  LCOL(0, cA)
  LCOL(1, cB)
  LCOL(2, cC)
  LCOL(3, cD)                              // depth-1 prefetch issued
#pragma unroll
  for (int j = 2; j < HSX; ++j) {
    // A) issue column j+2 (depth-2) -- pinned before compute
    if (j + 2 < HSX) { LCOL(j + 2, cE) }
    __builtin_amdgcn_sched_barrier(0);

    // B) compute output: tile row r0, tile column j-2 (halo col j-1)
    {
      f32x4 a = bq;
      a += wq[0] * cA[0];
      a += wq[1] * cB[0];
      a += wq[2] * cC[0];
      a += wq[3] * cA[1];
      a += wq[4] * cB[1];
      a += wq[5] * cC[1];
      a += wq[6] * cA[2];
      a += wq[7] * cB[2];
      a += wq[8] * cC[2];
      f32x4 res;
#pragma unroll
      for (int cc = 0; cc < 4; ++cc)
        res[cc] = cB[1][cc] + gelu_fast(a[cc]);
      const int n = HIDX(HSX + (j - 1));   // center row (r=1), halo col j-1
      __builtin_nontemporal_store(res, (f32x4*)(ob + ((size_t)n << 8) + c4));
    }
    // C) rotate window (SSA renames after full unroll)
#pragma unroll
    for (int r3 = 0; r3 < 3; ++r3) {
      cA[r3] = cB[r3];
      cB[r3] = cC[r3];
      cC[r3] = cD[r3];
      cD[r3] = cE[r3];
    }
  }
}

// ---------------------------------------------------------------------------
extern "C" void kernel_launch(void* const* d_in, const int* in_sizes, int n_in,
                              void* d_out, int out_size, void* d_ws,
                              size_t ws_size, hipStream_t stream) {
  const float* x = (const float*)d_in[0];
  const int* coords = (const int*)d_in[1];
  const float* cw = (const float*)d_in[2];
  const float* cb = (const float*)d_in[3];
  float* out = (float*)d_out;
  int* inv = (int*)d_ws;                        // B*N ints = 1 MiB
  float* zrow = (float*)d_ws + (size_t)BB * NN; // 256 floats after inv

  {
    dim3 grid((BB * NN) / 256), block(256);
    build_inv_kernel<<<grid, block, 0, stream>>>(coords, inv, zrow);
  }
  {
    dim3 grid(BB * (GW / TSY) * (GW / TSX)), block(256);   // 4096 blocks
    mixer_kernel<<<grid, block, 0, stream>>>(x, cw, cb, inv, zrow, out);
  }
}